// Round 32
// baseline (3546.827 us; speedup 1.0000x reference)
//
#include <hip/hip_runtime.h>

#define NTOK 197
#define BATCH 32
#define ROWS (BATCH*NTOK)   // 6304
#define EMB 768
#define FFDIM 3072
#define NHEAD 12
#define HDIM 64
#define NPAD 224            // padded key dim for PV GEMM

typedef __bf16 bf16x8_t __attribute__((ext_vector_type(8)));
typedef float f32x4 __attribute__((ext_vector_type(4)));
typedef unsigned short u16;
typedef u16 u16x4 __attribute__((ext_vector_type(4)));

__device__ __forceinline__ u16 f2b(float f) {
  union { float f; unsigned int u; } v; v.f = f;
  unsigned int r = v.u + 0x7fffu + ((v.u >> 16) & 1u);
  return (u16)(r >> 16);
}
__device__ __forceinline__ float b2f(u16 b) {
  union { unsigned int u; float f; } v; v.u = ((unsigned int)b) << 16;
  return v.f;
}
__device__ __forceinline__ void gload16(const void* g, void* l) {
  __builtin_amdgcn_global_load_lds((const __attribute__((address_space(1))) void*)g,
                                   (__attribute__((address_space(3))) void*)l, 16, 0, 0);
}
__device__ __forceinline__ float wred_sum(float v) {
#pragma unroll
  for (int o = 32; o > 0; o >>= 1) v += __shfl_xor(v, o);
  return v;
}

// Bijective XCD-aware block swizzle (m204).
__device__ __forceinline__ void xcd_swz(int& bx, int& by) {
  const int gx = gridDim.x;
  const int nwg = gx * gridDim.y;
  const int orig = by * gx + bx;
  const int q = nwg >> 3, r = nwg & 7;
  const int xcd = orig & 7, idx = orig >> 3;
  const int wg = (xcd < r ? xcd * (q + 1) : r * (q + 1) + (xcd - r) * q) + idx;
  by = wg / gx; bx = wg % gx;
}

// ------------- 256x128 tile, 8 waves, 2-DEEP prefetch + counted vmcnt -------------
// All projection/FFN/patch GEMMs. vmcnt(3): tile-kt loads complete, next tile's stay in
// flight; last iteration drains vmcnt(0). lgkmcnt(0)+sched_barrier before the reuse
// barrier orders cross-wave ds_read vs overwrite.
// Round 29 (kept, -10.5us): stage(kt+2) issued BEFORE the MFMA block (after the reuse
// barrier) — loads get ~1 extra MFMA-block of flight time. Semantics identical.
// NOTE (round 25): do NOT fuse the V-transpose into the epilogue (+198us).
// NOTE (round 27): do NOT shrink to 128x128 (doubled HBM FETCH; +195us).
template <bool HAS_BIAS, bool RELU, bool OUT_BF16>
__global__ __launch_bounds__(512)
void gemm_bt2(const u16* __restrict__ A, const u16* __restrict__ Bt, void* __restrict__ C,
              const float* __restrict__ bias, int M, int N, int K) {
  __shared__ __align__(16) char lds[2][24576];
  const int tid = threadIdx.x;
  const int lane = tid & 63;
  const int wid = tid >> 6;          // 0..7
  const int wm = wid >> 1, wn = wid & 1;
  int bxs = blockIdx.x, bys = blockIdx.y;
  xcd_swz(bxs, bys);
  const int bm = bys * 256, bn = bxs * 128;
  const int r15 = lane & 15, khi = lane >> 4;

  f32x4 acc[4][4] = {};
  const int nk = K >> 5;             // >= 2 for all callers

  auto stage = [&](int buf, int kt) {
    const int k0 = kt * 32 + khi * 8;
#pragma unroll
    for (int i = 0; i < 3; ++i) {    // 24 subtiles / 8 waves = 3 loads/wave
      int s = wid * 3 + i;
      char* ldst = &lds[buf][s * 1024];
      const u16* g;
      if (s < 16) {
        int row = bm + s * 16 + r15; if (row >= M) row = M - 1;
        g = A + (size_t)row * K + k0;
      } else {
        int row = bn + (s - 16) * 16 + r15;
        g = Bt + (size_t)row * K + k0;
      }
      gload16(g, ldst);
    }
  };

  stage(0, 0);
  stage(1, 1);
  for (int kt = 0; kt < nk; ++kt) {
    const int cur = kt & 1;
    if (kt + 1 < nk) { asm volatile("s_waitcnt vmcnt(3)" ::: "memory"); }
    else             { asm volatile("s_waitcnt vmcnt(0)" ::: "memory"); }
    __builtin_amdgcn_sched_barrier(0);
    __builtin_amdgcn_s_barrier();                     // everyone's tile-kt loads done
    bf16x8_t a[4], b[4];
#pragma unroll
    for (int mt = 0; mt < 4; ++mt)
      a[mt] = *(const bf16x8_t*)&lds[cur][(wm * 4 + mt) * 1024 + lane * 16];
#pragma unroll
    for (int nt = 0; nt < 4; ++nt)
      b[nt] = *(const bf16x8_t*)&lds[cur][16384 + (wn * 4 + nt) * 1024 + lane * 16];
    asm volatile("s_waitcnt lgkmcnt(0)" ::: "memory"); // fragments in registers
    __builtin_amdgcn_sched_barrier(0);
    __builtin_amdgcn_s_barrier();                      // all waves past their reads
    if (kt + 2 < nk) stage(cur, kt + 2);               // issue early: fly under MFMA
    __builtin_amdgcn_sched_barrier(0);                 // pin load-issue before MFMA
#pragma unroll
    for (int mt = 0; mt < 4; ++mt)
#pragma unroll
      for (int nt = 0; nt < 4; ++nt)
        acc[mt][nt] = __builtin_amdgcn_mfma_f32_16x16x32_bf16(a[mt], b[nt], acc[mt][nt], 0, 0, 0);
  }

#pragma unroll
  for (int mt = 0; mt < 4; ++mt) {
#pragma unroll
    for (int nt = 0; nt < 4; ++nt) {
      const int col = bn + wn * 64 + nt * 16 + r15;
      float bv = 0.f;
      if (HAS_BIAS) bv = bias[col];
#pragma unroll
      for (int j = 0; j < 4; ++j) {
        const int row = bm + wm * 64 + mt * 16 + khi * 4 + j;
        if (row < M) {
          float v = acc[mt][nt][j] + bv;
          if (RELU) v = v > 0.f ? v : 0.f;
          if (OUT_BF16) ((u16*)C)[(size_t)row * N + col] = f2b(v);
          else          ((float*)C)[(size_t)row * N + col] = v;
        }
      }
    }
  }
}

// ------------- split-K=3, 128x128, 2-DEEP prefetch + counted vmcnt(4), bf16 partials -------------
// Used for Wo (Kh=256, nk=8) and FFN2 (Kh=1024, nk=32). Partials are zero-mean sigma~0.2;
// bf16 rounding proved invisible on both paths (rounds 20/21: absmax unchanged).
// Round 29: same issue-early stage reorder as gemm_bt2.
__global__ __launch_bounds__(256)
void gemm_bt_sk_h(const u16* __restrict__ A, const u16* __restrict__ Bt,
                  u16* __restrict__ P0, u16* __restrict__ P1, u16* __restrict__ P2,
                  int M, int N, int K) {
  __shared__ __align__(16) char lds[2][16384];
  const int tid = threadIdx.x;
  const int lane = tid & 63;
  const int wid = tid >> 6;
  const int wm = wid >> 1, wn = wid & 1;
  int bxs = blockIdx.x, bys = blockIdx.y;
  xcd_swz(bxs, bys);
  const int bm = bys * 128, bn = bxs * 128;
  const int r15 = lane & 15, khi = lane >> 4;
  const int Kh = K / 3;
  const int kbase = blockIdx.z * Kh;
  u16* __restrict__ C = (blockIdx.z == 0) ? P0 : (blockIdx.z == 1 ? P1 : P2);

  f32x4 acc[4][4] = {};
  const int nk = Kh >> 5;

  auto stage = [&](int buf, int kt) {
    const int k0 = kbase + kt * 32 + khi * 8;
#pragma unroll
    for (int i = 0; i < 4; ++i) {
      int s = wid * 4 + i;
      char* ldst = &lds[buf][s * 1024];
      const u16* g;
      if (s < 8) {
        int row = bm + s * 16 + r15; if (row >= M) row = M - 1;
        g = A + (size_t)row * K + k0;
      } else {
        int row = bn + (s - 8) * 16 + r15;
        g = Bt + (size_t)row * K + k0;
      }
      gload16(g, ldst);
    }
  };

  stage(0, 0);
  stage(1, 1);
  for (int kt = 0; kt < nk; ++kt) {
    const int cur = kt & 1;
    if (kt + 1 < nk) { asm volatile("s_waitcnt vmcnt(4)" ::: "memory"); }
    else             { asm volatile("s_waitcnt vmcnt(0)" ::: "memory"); }
    __builtin_amdgcn_sched_barrier(0);
    __builtin_amdgcn_s_barrier();
    bf16x8_t a[4], b[4];
#pragma unroll
    for (int mt = 0; mt < 4; ++mt)
      a[mt] = *(const bf16x8_t*)&lds[cur][(wm * 4 + mt) * 1024 + lane * 16];
#pragma unroll
    for (int nt = 0; nt < 4; ++nt)
      b[nt] = *(const bf16x8_t*)&lds[cur][8192 + (wn * 4 + nt) * 1024 + lane * 16];
    asm volatile("s_waitcnt lgkmcnt(0)" ::: "memory");
    __builtin_amdgcn_sched_barrier(0);
    __builtin_amdgcn_s_barrier();
    if (kt + 2 < nk) stage(cur, kt + 2);
    __builtin_amdgcn_sched_barrier(0);
#pragma unroll
    for (int mt = 0; mt < 4; ++mt)
#pragma unroll
      for (int nt = 0; nt < 4; ++nt)
        acc[mt][nt] = __builtin_amdgcn_mfma_f32_16x16x32_bf16(a[mt], b[nt], acc[mt][nt], 0, 0, 0);
  }

#pragma unroll
  for (int mt = 0; mt < 4; ++mt) {
#pragma unroll
    for (int nt = 0; nt < 4; ++nt) {
      const int col = bn + wn * 64 + nt * 16 + r15;
#pragma unroll
      for (int j = 0; j < 4; ++j) {
        const int row = bm + wm * 64 + mt * 16 + khi * 4 + j;
        if (row < M) C[(size_t)row * N + col] = f2b(acc[mt][nt][j]);
      }
    }
  }
}

// ------- fused split-K(3) reduce + bias + residual + LayerNorm, bf16 partials -------
// 192 active lanes; u16x4/f32x4-vectorized.
// RES_BF16: residual read as bf16 (within-layer x residual; regenerated through LN each
//           layer so its rounding enters the persistent stream only once per layer).
// OUT_F32:  also store fp32 (needed only for the persistent h stream / LN2 output).
template <bool RES_BF16, bool OUT_F32>
__global__ __launch_bounds__(256)
void ln_red_h(const u16* __restrict__ P0, const u16* __restrict__ P1,
              const u16* __restrict__ P2,
              const float* __restrict__ bias, const void* __restrict__ res,
              const float* __restrict__ g, const float* __restrict__ bv,
              float* __restrict__ o32, u16* __restrict__ obf) {
  const int row = blockIdx.x;
  const size_t b4 = (size_t)row * 192;   // 4-wide index of row start
  const int tid = threadIdx.x;
  f32x4 vv = {0.f, 0.f, 0.f, 0.f};
  float ls = 0.f, lq = 0.f;
  if (tid < 192) {
    u16x4 a = ((const u16x4*)P0)[b4 + tid];
    u16x4 b = ((const u16x4*)P1)[b4 + tid];
    u16x4 p = ((const u16x4*)P2)[b4 + tid];
    f32x4 c;
    if constexpr (RES_BF16) {
      u16x4 cr = ((const u16x4*)res)[b4 + tid];
#pragma unroll
      for (int k = 0; k < 4; ++k) c[k] = b2f(cr[k]);
    } else {
      c = ((const f32x4*)res)[b4 + tid];
    }
    f32x4 d = ((const f32x4*)bias)[tid];
#pragma unroll
    for (int k = 0; k < 4; ++k)
      vv[k] = b2f(a[k]) + b2f(b[k]) + b2f(p[k]) + c[k] + d[k];
    ls = vv[0] + vv[1] + vv[2] + vv[3];
    lq = vv[0]*vv[0] + vv[1]*vv[1] + vv[2]*vv[2] + vv[3]*vv[3];
  }
  float s = wred_sum(ls);
  float s2 = wred_sum(lq);
  __shared__ float rs[4], rq[4];
  const int wv = tid >> 6, lane = tid & 63;
  if (lane == 0) { rs[wv] = s; rq[wv] = s2; }
  __syncthreads();
  float S1 = rs[0] + rs[1] + rs[2] + rs[3];
  float S2 = rq[0] + rq[1] + rq[2] + rq[3];
  float mean = S1 * (1.0f / 768.0f);
  float var = S2 * (1.0f / 768.0f) - mean * mean;
  float inv = rsqrtf(var + 1e-5f);
  if (tid < 192) {
    f32x4 gg = ((const f32x4*)g)[tid];
    f32x4 bb = ((const f32x4*)bv)[tid];
    f32x4 y;
    u16x4 ob;
#pragma unroll
    for (int k = 0; k < 4; ++k) {
      y[k] = (vv[k] - mean) * inv * gg[k] + bb[k];
      ob[k] = f2b(y[k]);
    }
    if constexpr (OUT_F32) ((f32x4*)o32)[b4 + tid] = y;
    ((u16x4*)obf)[b4 + tid] = ob;
  }
}

// ------- per-layer weight prep: fp32 [K,N] -> bf16 [N,K] for all 6 matrices -------
__global__ void prep_layer(const float* __restrict__ Wq, const float* __restrict__ Wk,
                           const float* __restrict__ Wv, const float* __restrict__ Wo,
                           const float* __restrict__ W1, const float* __restrict__ W2,
                           u16* __restrict__ qkvT, u16* __restrict__ woT,
                           u16* __restrict__ w1T, u16* __restrict__ w2T) {
  __shared__ float tbuf[32][33];
  const int t = blockIdx.x;
  const float* src; u16* dst; int K, N, nt, kt;
  if (t < 2304) {
    int seg = t / 576, r = t % 576;
    nt = r % 24; kt = r / 24; K = 768; N = 768;
    if (seg == 0)      { src = Wq; dst = qkvT; }
    else if (seg == 1) { src = Wk; dst = qkvT + (size_t)768 * 768; }
    else if (seg == 2) { src = Wv; dst = qkvT + (size_t)2 * 768 * 768; }
    else               { src = Wo; dst = woT; }
  } else if (t < 4608) {
    int r = t - 2304; nt = r % 96; kt = r / 96;
    K = 768; N = 3072; src = W1; dst = w1T;
  } else {
    int r = t - 4608; nt = r % 24; kt = r / 24;
    K = 3072; N = 768; src = W2; dst = w2T;
  }
  const int n0 = nt * 32, k0 = kt * 32;
  const int tx = threadIdx.x, ty = threadIdx.y;  // (32,8)
#pragma unroll
  for (int i = 0; i < 4; ++i)
    tbuf[ty + i * 8][tx] = src[(size_t)(k0 + ty + i * 8) * N + n0 + tx];
  __syncthreads();
#pragma unroll
  for (int i = 0; i < 4; ++i)
    dst[(size_t)(n0 + ty + i * 8) * K + k0 + tx] = f2b(tbuf[tx][ty + i * 8]);
}

__global__ void convert_bf(const float* __restrict__ s, u16* __restrict__ d, size_t n) {
  size_t i = (size_t)blockIdx.x * 256 + threadIdx.x;
  if (i < n) d[i] = f2b(s[i]);
}

// ---- head_W transpose: fp32 [768,1000] -> fp32 [1000,768] ----
__global__ void transpose_head(const float* __restrict__ src, float* __restrict__ dst) {
  __shared__ float tbuf[32][33];
  const int n0 = blockIdx.x * 32, k0 = blockIdx.y * 32;
  const int tx = threadIdx.x, ty = threadIdx.y;  // (32,8)
#pragma unroll
  for (int i = 0; i < 4; ++i) {
    int k = k0 + ty + i * 8, n = n0 + tx;
    if (n < 1000) tbuf[ty + i * 8][tx] = src[(size_t)k * 1000 + n];
  }
  __syncthreads();
#pragma unroll
  for (int i = 0; i < 4; ++i) {
    int n = n0 + ty + i * 8, k = k0 + tx;
    if (n < 1000) dst[(size_t)n * 768 + k] = tbuf[tx][ty + i * 8];
  }
}

// ---------------- patch im2col: A[b*196+p][c*256+ph*16+pw] ----------------
__global__ void im2col(const float* __restrict__ x, u16* __restrict__ A) {
  size_t idx = (size_t)blockIdx.x * 256 + threadIdx.x;
  if (idx >= (size_t)6272 * 768) return;
  int k = (int)(idx % 768); size_t row = idx / 768;
  int b = (int)(row / 196), p = (int)(row % 196);
  int py = p / 14, px = p % 14;
  int c = k >> 8, rem = k & 255, ph = rem >> 4, pw = rem & 15;
  float v = x[(((size_t)b * 3 + c) * 224 + (py * 16 + ph)) * 224 + (px * 16 + pw)];
  A[idx] = f2b(v);
}

// ---------------- h0 = concat(cls, patches) + pos ----------------
__global__ void assemble_h0(const float* __restrict__ pout, const float* __restrict__ cls,
                            const float* __restrict__ pos, float* __restrict__ h32,
                            u16* __restrict__ hbf) {
  const int row = blockIdx.x;           // 0..6303
  const int b = row / NTOK, n = row % NTOK;
  for (int c = threadIdx.x; c < EMB; c += 256) {
    float v;
    if (n == 0) v = cls[c] + pos[c];
    else v = pout[((size_t)b * 196 + (n - 1)) * EMB + c] + pos[(size_t)n * EMB + c];
    h32[(size_t)row * EMB + c] = v;
    hbf[(size_t)row * EMB + c] = f2b(v);
  }
}

// ------- vT[bh][d][n] = v[b][n][h][d] via LDS tile transpose (both sides coalesced) -------
// grid (14, 384): blockIdx.x = dt*7 + nt  (dt 0..1 selects 32-d half, nt 0..6 selects 32-n tile)
__global__ void build_vT2(const u16* __restrict__ qkv, u16* __restrict__ vT) {
  __shared__ u16 tbuf[32][34];
  const int t = blockIdx.x;
  const int dt = t / 7, nt = t % 7;
  const int bh = blockIdx.y;
  const int b = bh / NHEAD, h = bh % NHEAD;
  const int tx = threadIdx.x, ty = threadIdx.y;  // (32,8)
  const u16* vbase = qkv + (size_t)b * NTOK * 2304 + 1536 + h * HDIM + dt * 32;
#pragma unroll
  for (int i = 0; i < 4; ++i) {
    int nrow = ty + i * 8;                // 0..31 (nn-local)
    int nn = nt * 32 + nrow;
    u16 v = 0;
    if (nn < NTOK) v = vbase[(size_t)nn * 2304 + tx];   // tx = d-local: coalesced (2B stride)
    tbuf[nrow][tx] = v;
  }
  __syncthreads();
  u16* obase = vT + ((size_t)bh * HDIM + dt * 32) * NPAD + nt * 32;
#pragma unroll
  for (int i = 0; i < 4; ++i) {
    int drow = ty + i * 8;                // 0..31 (d-local)
    obase[(size_t)drow * NPAD + tx] = tbuf[tx][drow];   // tx = nn-local: coalesced
  }
}

// ---------------- fused scores + softmax for a 32-q-row slab of one (b,h) ----------------
__global__ __launch_bounds__(256)
void attn_sm(const u16* __restrict__ qkv, u16* __restrict__ P) {
  __shared__ __align__(16) char kf[13 * 2 * 1024];  // 26KB, K fragments
  __shared__ __align__(16) char qf[2 * 2 * 1024];   // 4KB,  Q fragments
  __shared__ float S[32][NPAD + 4];                 // 28.5KB (bank-conflict pad)
  const int bh = blockIdx.y;
  const int b = bh / NHEAD, h = bh % NHEAD;
  const int qb = blockIdx.x;  // 0..6
  const int tid = threadIdx.x, lane = tid & 63, wid = tid >> 6;
  const int r15 = lane & 15, khi = lane >> 4;

  const u16* qbase = qkv + (size_t)b * NTOK * 2304 + h * HDIM;
  const u16* kbase = qbase + 768;

  for (int i = wid; i < 26; i += 4) {           // stage K: 13 subtiles x 2 kslices
    int sub = i >> 1, ks = i & 1;
    int row = sub * 16 + r15; if (row > 196) row = 196;
    gload16(kbase + (size_t)row * 2304 + ks * 32 + khi * 8, &kf[(size_t)i * 1024]);
  }
  {                                             // stage Q: 2 subtiles x 2 kslices
    int i = wid;  // 0..3
    int sub = i >> 1, ks = i & 1;
    int row = qb * 32 + sub * 16 + r15; if (row > 196) row = 196;
    gload16(qbase + (size_t)row * 2304 + ks * 32 + khi * 8, &qf[(size_t)i * 1024]);
  }
  __syncthreads();

  const float scale = 0.03608439182435161f;  // 1/sqrt(768)
  for (int t = wid; t < 26; t += 4) {
    int qi = t / 13, ki = t % 13;
    f32x4 acc = {};
    bf16x8_t aq0 = *(const bf16x8_t*)&qf[(qi * 2 + 0) * 1024 + lane * 16];
    bf16x8_t aq1 = *(const bf16x8_t*)&qf[(qi * 2 + 1) * 1024 + lane * 16];
    bf16x8_t bk0 = *(const bf16x8_t*)&kf[(ki * 2 + 0) * 1024 + lane * 16];
    bf16x8_t bk1 = *(const bf16x8_t*)&kf[(ki * 2 + 1) * 1024 + lane * 16];
    acc = __builtin_amdgcn_mfma_f32_16x16x32_bf16(aq0, bk0, acc, 0, 0, 0);
    acc = __builtin_amdgcn_mfma_f32_16x16x32_bf16(aq1, bk1, acc, 0, 0, 0);
#pragma unroll
    for (int j = 0; j < 4; ++j) S[qi * 16 + khi * 4 + j][ki * 16 + r15] = acc[j] * scale;
  }
  __syncthreads();

  for (int i = 0; i < 8; ++i) {
    const int r = wid * 8 + i;
    const int q = qb * 32 + r;
    if (q > 196) continue;
    float vals[4]; float m = -1e30f;
#pragma unroll
    for (int c = 0; c < 4; ++c) {
      int col = lane + c * 64;
      float v = (col < NTOK) ? S[r][col] : -1e30f;
      vals[c] = v; m = fmaxf(m, v);
    }
#pragma unroll
    for (int o = 32; o > 0; o >>= 1) m = fmaxf(m, __shfl_xor(m, o));
    float s = 0.f;
#pragma unroll
    for (int c = 0; c < 4; ++c) { float e = __expf(vals[c] - m); vals[c] = e; s += e; }
    s = wred_sum(s);
    float inv = 1.f / s;
    u16* prow = P + ((size_t)bh * NTOK + q) * NPAD;
#pragma unroll
    for (int c = 0; c < 4; ++c) {
      int col = lane + c * 64;
      if (col < NPAD) prow[col] = f2b(vals[c] * inv);
    }
  }
}

// ------- PV half-split: grid (2, 384); z selects P subtiles 0..6 / 7..12 -------
__global__ __launch_bounds__(256)
void attn_pv_half(const u16* __restrict__ P, const u16* __restrict__ vT,
                  u16* __restrict__ out) {
  __shared__ __align__(16) char lds[2][11 * 1024];  // P subtiles 0..6, V subtiles 7..10
  const int z = blockIdx.x;          // 0: q-subtiles 0..6, 1: 7..12
  const int bh = blockIdx.y;
  const int b = bh / NHEAD, h = bh % NHEAD;
  const int qoff = z ? 7 : 0;
  const int NQ = z ? 6 : 7;
  const int tid = threadIdx.x, lane = tid & 63, wid = tid >> 6;
  const int r15 = lane & 15, khi = lane >> 4;
  const u16* Pb = P + (size_t)bh * NTOK * NPAD;
  const u16* Vb = vT + (size_t)bh * HDIM * NPAD;

  f32x4 acc[2][4] = {};
  auto stage = [&](int buf, int kt) {
    for (int i = wid; i < 11; i += 4) {
      const u16* g;
      if (i < 7) { int sub = qoff + i; if (sub > 12) sub = 12;   // z=1,i=6: dup, never stored
                   int row = sub * 16 + r15; if (row > 196) row = 196;
                   g = Pb + (size_t)row * NPAD + kt * 32 + khi * 8; }
      else       { int row = (i - 7) * 16 + r15;
                   g = Vb + (size_t)row * NPAD + kt * 32 + khi * 8; }
      gload16(g, &lds[buf][i * 1024]);
    }
  };
  stage(0, 0);
  __syncthreads();
  for (int kt = 0; kt < 7; ++kt) {
    const int cur = kt & 1;
    if (kt + 1 < 7) stage(cur ^ 1, kt + 1);
    bf16x8_t bb[4];
#pragma unroll
    for (int di = 0; di < 4; ++di)
      bb[di] = *(const bf16x8_t*)&lds[cur][(7 + di) * 1024 + lane * 16];
#pragma unroll
    for (int s = 0; s < 2; ++s) {
      int ql = wid + s * 4;
      if (ql < NQ) {
        bf16x8_t a = *(const bf16x8_t*)&lds[cur][ql * 1024 + lane * 16];
#pragma unroll
        for (int di = 0; di < 4; ++di)
          acc[s][di] = __builtin_amdgcn_mfma_f32_16x16x32_bf16(a, bb[di], acc[s][di], 0, 0, 0);
      }
    }
    __syncthreads();
  }
#pragma unroll
  for (int s = 0; s < 2; ++s) {
    int ql = wid + s * 4;
    if (ql >= NQ) continue;
    const int qi = qoff + ql;
#pragma unroll
    for (int di = 0; di < 4; ++di) {
      int col = h * HDIM + di * 16 + r15;
#pragma unroll
      for (int j = 0; j < 4; ++j) {
        int q = qi * 16 + khi * 4 + j;
        if (q < NTOK) out[((size_t)b * NTOK + q) * EMB + col] = f2b(acc[s][di][j]);
      }
    }
  }
}

// ---------------- LN of the 32 cls rows -> cls_ln[32][768] fp32 ----------------
__global__ __launch_bounds__(256)
void ln_cls(const float* __restrict__ h32, const float* __restrict__ hg,
            const float* __restrict__ hb, float* __restrict__ cls_ln) {
  const int b = blockIdx.x;
  const float* xr = h32 + (size_t)b * NTOK * EMB;  // row n=0
  const int tid = threadIdx.x;
  float v0 = xr[tid], v1 = xr[tid + 256], v2 = xr[tid + 512];
  float s = wred_sum(v0 + v1 + v2);
  float s2 = wred_sum(v0 * v0 + v1 * v1 + v2 * v2);
  __shared__ float rs[4], rq[4];
  const int wid = tid >> 6, lane = tid & 63;
  if (lane == 0) { rs[wid] = s; rq[wid] = s2; }
  __syncthreads();
  float S1 = rs[0] + rs[1] + rs[2] + rs[3];
  float S2 = rq[0] + rq[1] + rq[2] + rq[3];
  float mean = S1 * (1.0f / 768.0f);
  float var = S2 * (1.0f / 768.0f) - mean * mean;
  float inv = rsqrtf(var + 1e-5f);
  cls_ln[(size_t)b * EMB + tid]       = (v0 - mean) * inv * hg[tid]       + hb[tid];
  cls_ln[(size_t)b * EMB + tid + 256] = (v1 - mean) * inv * hg[tid + 256] + hb[tid + 256];
  cls_ln[(size_t)b * EMB + tid + 512] = (v2 - mean) * inv * hg[tid + 512] + hb[tid + 512];
}

// -------- head2: out[b][j] = dot(cls_ln[b], hWT[j]) + bias[j]; one wave per output --------
__global__ __launch_bounds__(256)
void head2(const float* __restrict__ cls_ln, const float* __restrict__ hWT,
           const float* __restrict__ bias, float* __restrict__ out) {
  __shared__ float t[EMB];
  const int b = blockIdx.y;
  const int tid = threadIdx.x, lane = tid & 63, wid = tid >> 6;
  t[tid] = cls_ln[(size_t)b * EMB + tid];
  t[tid + 256] = cls_ln[(size_t)b * EMB + tid + 256];
  t[tid + 512] = cls_ln[(size_t)b * EMB + tid + 512];
  __syncthreads();
  const int j = blockIdx.x * 4 + wid;   // 250*4 = 1000 exactly
  const float* wr = hWT + (size_t)j * EMB;
  float a = 0.f;
#pragma unroll
  for (int i = 0; i < 12; ++i) {
    int e = lane + i * 64;
    a += t[e] * wr[e];
  }
  a = wred_sum(a);
  if (lane == 0) out[(size_t)b * 1000 + j] = a + bias[j];
}

extern "C" void kernel_launch(void* const* d_in, const int* in_sizes, int n_in,
                              void* d_out, int out_size, void* d_ws, size_t ws_size,
                              hipStream_t stream) {
  const float* x      = (const float*)d_in[0];
  const float* conv_w = (const float*)d_in[1];
  const float* conv_b = (const float*)d_in[2];
  const float* cls    = (const float*)d_in[3];
  const float* pos    = (const float*)d_in[4];
  const float* Wq     = (const float*)d_in[5];
  const float* Wk     = (const float*)d_in[6];
  const float* Wv     = (const float*)d_in[7];
  const float* Wo     = (const float*)d_in[8];
  const float* bo     = (const float*)d_in[9];
  const float* ln1g   = (const float*)d_in[10];
  const float* ln1b   = (const float*)d_in[11];
  const float* W1     = (const float*)d_in[12];
  const float* b1     = (const float*)d_in[13];
  const float* W2     = (const float*)d_in[14];
  const float* b2     = (const float*)d_in[15];
  const float* ln2g   = (const float*)d_in[16];
  const float* ln2b   = (const float*)d_in[17];
  const float* hg     = (const float*)d_in[18];
  const float* hb     = (const float*)d_in[19];
  const float* hW     = (const float*)d_in[20];
  const float* hbias  = (const float*)d_in[21];

  char* ws = (char*)d_ws;
  size_t off = 0;
  auto alloc = [&](size_t bytes) { void* p = ws + off; off += (bytes + 255) & ~(size_t)255; return p; };

  // per-layer transposed weights (reused every layer)
  u16*   qkvT = (u16*)alloc((size_t)2304 * 768 * 2);            // 3.54 MB
  u16*   woTl = (u16*)alloc((size_t)768 * 768 * 2);             // 1.18 MB
  u16*   w1Tl = (u16*)alloc((size_t)3072 * 768 * 2);            // 4.72 MB
  u16*   w2Tl = (u16*)alloc((size_t)768 * 3072 * 2);            // 4.72 MB
  u16*   cw   = (u16*)alloc((size_t)768 * 768 * 2);             // 1.18 MB
  float* h32  = (float*)alloc((size_t)ROWS * EMB * 4);          // 19.4 MB (persistent fp32 stream)
  u16*   hbf  = (u16*)alloc((size_t)ROWS * EMB * 2);            // 9.7 MB
  u16*   qkv  = (u16*)alloc((size_t)ROWS * 2304 * 2);           // 29.0 MB (also FFN2 bf16 partials)
  u16*   vT   = (u16*)alloc((size_t)384 * HDIM * NPAD * 2);     // 11.0 MB
  // union region (38.8MB): {Pbuf 33.9} OR {Wo bf16 partials 3x9.7} OR {mid 38.7} OR {pout 19.3}
  char*  big  = (char*)alloc(2 * (size_t)ROWS * EMB * 4);       // 38.8 MB
  u16*   Pbuf = (u16*)big;
  u16*   mid  = (u16*)big;                   // FFN hidden, alive only after attn done
  float* pout = (float*)big;                 // setup-phase patch GEMM output
  u16*   woPh0 = (u16*)big;                              // Wo bf16 partial 0 (Pbuf dead)
  u16*   woPh1 = (u16*)(big + (size_t)ROWS * EMB * 2);   // partial 1
  u16*   woPh2 = (u16*)(big + (size_t)2 * ROWS * EMB * 2); // partial 2 (29.1MB total < 38.8)
  u16*   att  = (u16*)alloc((size_t)ROWS * EMB * 2);            // 9.7 MB  (aliased w/ xbf)
  u16*   xbf  = att;                         // bf16 x: FFN1 input AND LN2 residual
  float* hWT  = (float*)alloc((size_t)1000 * EMB * 4);          // 3.07 MB
  float* clsl = (float*)alloc((size_t)32 * EMB * 4);            // 98 KB
  u16*   Apatch = qkv;                       // setup-phase im2col output (9.6MB < 29MB)
  // FFN2 bf16 partials live in qkv (dead after attention; 3 x 9.68MB = 29.04MB = qkv size)
  u16*   f2Ph0 = qkv;
  u16*   f2Ph1 = qkv + (size_t)ROWS * EMB;
  u16*   f2Ph2 = qkv + (size_t)2 * ROWS * EMB;

  if (off > ws_size) return;  // workspace too small: fail validation cleanly, never write OOB

  // ---- conv weight + head weight + patch embed (256x128 pipelined GEMM) ----
  convert_bf<<<2304, 256, 0, stream>>>(conv_w, cw, (size_t)768 * 768);
  transpose_head<<<dim3(32, 24), dim3(32, 8), 0, stream>>>(hW, hWT);
  im2col<<<18816, 256, 0, stream>>>(x, Apatch);
  gemm_bt2<true, false, false><<<dim3(6, 25), 512, 0, stream>>>(
      Apatch, cw, pout, conv_b, 6272, 768, 768);
  assemble_h0<<<ROWS, 256, 0, stream>>>(pout, cls, pos, h32, hbf);

  // ---- transformer layers ----
  for (int l = 0; l < 12; ++l) {
    const size_t wo = (size_t)l * 768 * 768;
    prep_layer<<<6912, dim3(32, 8), 0, stream>>>(
        Wq + wo, Wk + wo, Wv + wo, Wo + wo,
        W1 + (size_t)l * 768 * 3072, W2 + (size_t)l * 3072 * 768,
        qkvT, woTl, w1Tl, w2Tl);
    // QKV: 256x128 8-wave tile, 2-deep counted-vmcnt pipeline, issue-early staging
    gemm_bt2<false, false, true><<<dim3(18, 25), 512, 0, stream>>>(
        hbf, qkvT, qkv, nullptr, ROWS, 2304, 768);
    build_vT2<<<dim3(14, 384), dim3(32, 8), 0, stream>>>(qkv, vT);
    attn_sm<<<dim3(7, 384), 256, 0, stream>>>(qkv, Pbuf);
    attn_pv_half<<<dim3(2, 384), 256, 0, stream>>>(Pbuf, vT, att);
    // Wo projection, split-K=3 (Kh=256), bf16 partials; LN1: fp32 res (h32), bf16-only out
    gemm_bt_sk_h<<<dim3(6, 50, 3), 256, 0, stream>>>(att, woTl, woPh0, woPh1, woPh2, ROWS, 768, 768);
    ln_red_h<false, false><<<ROWS, 256, 0, stream>>>(
        woPh0, woPh1, woPh2, bo + (size_t)l * 768, h32,
        ln1g + (size_t)l * 768, ln1b + (size_t)l * 768, nullptr, xbf);
    // FFN1: 256x128 8-wave tile, fused bias+relu+bf16
    gemm_bt2<true, true, true><<<dim3(24, 25), 512, 0, stream>>>(
        xbf, w1Tl, mid, b1 + (size_t)l * 3072, ROWS, FFDIM, 768);
    // FFN2, split-K=3 (Kh=1024), bf16 partials (in dead qkv); LN2: bf16 res (xbf),
    // fp32+bf16 out (persistent h stream stays fp32)
    gemm_bt_sk_h<<<dim3(6, 50, 3), 256, 0, stream>>>(mid, w2Tl, f2Ph0, f2Ph1, f2Ph2, ROWS, 768, FFDIM);
    ln_red_h<true, true><<<ROWS, 256, 0, stream>>>(
        f2Ph0, f2Ph1, f2Ph2, b2 + (size_t)l * 768, xbf,
        ln2g + (size_t)l * 768, ln2b + (size_t)l * 768, h32, hbf);
  }

  // ---- classifier head ----
  ln_cls<<<32, 256, 0, stream>>>(h32, hg, hb, clsl);
  head2<<<dim3(250, 32), 256, 0, stream>>>(clsl, hWT, hbias, (float*)d_out);
}

// Round 33
// 3544.072 us; speedup vs baseline: 1.0008x; 1.0008x over previous
//
#include <hip/hip_runtime.h>

#define NTOK 197
#define BATCH 32
#define ROWS (BATCH*NTOK)   // 6304
#define EMB 768
#define FFDIM 3072
#define NHEAD 12
#define HDIM 64
#define NPAD 224            // padded key dim for PV GEMM

typedef __bf16 bf16x8_t __attribute__((ext_vector_type(8)));
typedef float f32x4 __attribute__((ext_vector_type(4)));
typedef unsigned short u16;
typedef u16 u16x4 __attribute__((ext_vector_type(4)));

__device__ __forceinline__ u16 f2b(float f) {
  union { float f; unsigned int u; } v; v.f = f;
  unsigned int r = v.u + 0x7fffu + ((v.u >> 16) & 1u);
  return (u16)(r >> 16);
}
__device__ __forceinline__ float b2f(u16 b) {
  union { unsigned int u; float f; } v; v.u = ((unsigned int)b) << 16;
  return v.f;
}
__device__ __forceinline__ void gload16(const void* g, void* l) {
  __builtin_amdgcn_global_load_lds((const __attribute__((address_space(1))) void*)g,
                                   (__attribute__((address_space(3))) void*)l, 16, 0, 0);
}
__device__ __forceinline__ float wred_sum(float v) {
#pragma unroll
  for (int o = 32; o > 0; o >>= 1) v += __shfl_xor(v, o);
  return v;
}

// Bijective XCD-aware block swizzle (m204).
__device__ __forceinline__ void xcd_swz(int& bx, int& by) {
  const int gx = gridDim.x;
  const int nwg = gx * gridDim.y;
  const int orig = by * gx + bx;
  const int q = nwg >> 3, r = nwg & 7;
  const int xcd = orig & 7, idx = orig >> 3;
  const int wg = (xcd < r ? xcd * (q + 1) : r * (q + 1) + (xcd - r) * q) + idx;
  by = wg / gx; bx = wg % gx;
}

// ------------- 256x128 tile, 8 waves, 2-DEEP prefetch + counted vmcnt -------------
// All projection/FFN/patch GEMMs. vmcnt(3): tile-kt loads complete, next tile's stay in
// flight; last iteration drains vmcnt(0). lgkmcnt(0)+sched_barrier before the reuse
// barrier orders cross-wave ds_read vs overwrite.
// Round 29 (kept, -10.5us): stage(kt+2) issued BEFORE the MFMA block (after the reuse
// barrier) — loads get ~1 extra MFMA-block of flight time. Semantics identical.
// NOTE (round 25): do NOT fuse the V-transpose into the epilogue (+198us).
// NOTE (round 27): do NOT shrink to 128x128 (doubled HBM FETCH; +195us).
template <bool HAS_BIAS, bool RELU, bool OUT_BF16>
__global__ __launch_bounds__(512)
void gemm_bt2(const u16* __restrict__ A, const u16* __restrict__ Bt, void* __restrict__ C,
              const float* __restrict__ bias, int M, int N, int K) {
  __shared__ __align__(16) char lds[2][24576];
  const int tid = threadIdx.x;
  const int lane = tid & 63;
  const int wid = tid >> 6;          // 0..7
  const int wm = wid >> 1, wn = wid & 1;
  int bxs = blockIdx.x, bys = blockIdx.y;
  xcd_swz(bxs, bys);
  const int bm = bys * 256, bn = bxs * 128;
  const int r15 = lane & 15, khi = lane >> 4;

  f32x4 acc[4][4] = {};
  const int nk = K >> 5;             // >= 2 for all callers

  auto stage = [&](int buf, int kt) {
    const int k0 = kt * 32 + khi * 8;
#pragma unroll
    for (int i = 0; i < 3; ++i) {    // 24 subtiles / 8 waves = 3 loads/wave
      int s = wid * 3 + i;
      char* ldst = &lds[buf][s * 1024];
      const u16* g;
      if (s < 16) {
        int row = bm + s * 16 + r15; if (row >= M) row = M - 1;
        g = A + (size_t)row * K + k0;
      } else {
        int row = bn + (s - 16) * 16 + r15;
        g = Bt + (size_t)row * K + k0;
      }
      gload16(g, ldst);
    }
  };

  stage(0, 0);
  stage(1, 1);
  for (int kt = 0; kt < nk; ++kt) {
    const int cur = kt & 1;
    if (kt + 1 < nk) { asm volatile("s_waitcnt vmcnt(3)" ::: "memory"); }
    else             { asm volatile("s_waitcnt vmcnt(0)" ::: "memory"); }
    __builtin_amdgcn_sched_barrier(0);
    __builtin_amdgcn_s_barrier();                     // everyone's tile-kt loads done
    bf16x8_t a[4], b[4];
#pragma unroll
    for (int mt = 0; mt < 4; ++mt)
      a[mt] = *(const bf16x8_t*)&lds[cur][(wm * 4 + mt) * 1024 + lane * 16];
#pragma unroll
    for (int nt = 0; nt < 4; ++nt)
      b[nt] = *(const bf16x8_t*)&lds[cur][16384 + (wn * 4 + nt) * 1024 + lane * 16];
    asm volatile("s_waitcnt lgkmcnt(0)" ::: "memory"); // fragments in registers
    __builtin_amdgcn_sched_barrier(0);
    __builtin_amdgcn_s_barrier();                      // all waves past their reads
    if (kt + 2 < nk) stage(cur, kt + 2);               // issue early: fly under MFMA
    __builtin_amdgcn_sched_barrier(0);                 // pin load-issue before MFMA
#pragma unroll
    for (int mt = 0; mt < 4; ++mt)
#pragma unroll
      for (int nt = 0; nt < 4; ++nt)
        acc[mt][nt] = __builtin_amdgcn_mfma_f32_16x16x32_bf16(a[mt], b[nt], acc[mt][nt], 0, 0, 0);
  }

#pragma unroll
  for (int mt = 0; mt < 4; ++mt) {
#pragma unroll
    for (int nt = 0; nt < 4; ++nt) {
      const int col = bn + wn * 64 + nt * 16 + r15;
      float bv = 0.f;
      if (HAS_BIAS) bv = bias[col];
#pragma unroll
      for (int j = 0; j < 4; ++j) {
        const int row = bm + wm * 64 + mt * 16 + khi * 4 + j;
        if (row < M) {
          float v = acc[mt][nt][j] + bv;
          if (RELU) v = v > 0.f ? v : 0.f;
          if (OUT_BF16) ((u16*)C)[(size_t)row * N + col] = f2b(v);
          else          ((float*)C)[(size_t)row * N + col] = v;
        }
      }
    }
  }
}

// ------------- split-K=3, 128x128, 2-DEEP prefetch + counted vmcnt(4), bf16 partials -------------
// Used for Wo (Kh=256, nk=8) and FFN2 (Kh=1024, nk=32). Partials are zero-mean sigma~0.2;
// bf16 rounding proved invisible on both paths (rounds 20/21: absmax unchanged).
// Round 29: same issue-early stage reorder as gemm_bt2.
__global__ __launch_bounds__(256)
void gemm_bt_sk_h(const u16* __restrict__ A, const u16* __restrict__ Bt,
                  u16* __restrict__ P0, u16* __restrict__ P1, u16* __restrict__ P2,
                  int M, int N, int K) {
  __shared__ __align__(16) char lds[2][16384];
  const int tid = threadIdx.x;
  const int lane = tid & 63;
  const int wid = tid >> 6;
  const int wm = wid >> 1, wn = wid & 1;
  int bxs = blockIdx.x, bys = blockIdx.y;
  xcd_swz(bxs, bys);
  const int bm = bys * 128, bn = bxs * 128;
  const int r15 = lane & 15, khi = lane >> 4;
  const int Kh = K / 3;
  const int kbase = blockIdx.z * Kh;
  u16* __restrict__ C = (blockIdx.z == 0) ? P0 : (blockIdx.z == 1 ? P1 : P2);

  f32x4 acc[4][4] = {};
  const int nk = Kh >> 5;

  auto stage = [&](int buf, int kt) {
    const int k0 = kbase + kt * 32 + khi * 8;
#pragma unroll
    for (int i = 0; i < 4; ++i) {
      int s = wid * 4 + i;
      char* ldst = &lds[buf][s * 1024];
      const u16* g;
      if (s < 8) {
        int row = bm + s * 16 + r15; if (row >= M) row = M - 1;
        g = A + (size_t)row * K + k0;
      } else {
        int row = bn + (s - 8) * 16 + r15;
        g = Bt + (size_t)row * K + k0;
      }
      gload16(g, ldst);
    }
  };

  stage(0, 0);
  stage(1, 1);
  for (int kt = 0; kt < nk; ++kt) {
    const int cur = kt & 1;
    if (kt + 1 < nk) { asm volatile("s_waitcnt vmcnt(4)" ::: "memory"); }
    else             { asm volatile("s_waitcnt vmcnt(0)" ::: "memory"); }
    __builtin_amdgcn_sched_barrier(0);
    __builtin_amdgcn_s_barrier();
    bf16x8_t a[4], b[4];
#pragma unroll
    for (int mt = 0; mt < 4; ++mt)
      a[mt] = *(const bf16x8_t*)&lds[cur][(wm * 4 + mt) * 1024 + lane * 16];
#pragma unroll
    for (int nt = 0; nt < 4; ++nt)
      b[nt] = *(const bf16x8_t*)&lds[cur][8192 + (wn * 4 + nt) * 1024 + lane * 16];
    asm volatile("s_waitcnt lgkmcnt(0)" ::: "memory");
    __builtin_amdgcn_sched_barrier(0);
    __builtin_amdgcn_s_barrier();
    if (kt + 2 < nk) stage(cur, kt + 2);
    __builtin_amdgcn_sched_barrier(0);
#pragma unroll
    for (int mt = 0; mt < 4; ++mt)
#pragma unroll
      for (int nt = 0; nt < 4; ++nt)
        acc[mt][nt] = __builtin_amdgcn_mfma_f32_16x16x32_bf16(a[mt], b[nt], acc[mt][nt], 0, 0, 0);
  }

#pragma unroll
  for (int mt = 0; mt < 4; ++mt) {
#pragma unroll
    for (int nt = 0; nt < 4; ++nt) {
      const int col = bn + wn * 64 + nt * 16 + r15;
#pragma unroll
      for (int j = 0; j < 4; ++j) {
        const int row = bm + wm * 64 + mt * 16 + khi * 4 + j;
        if (row < M) C[(size_t)row * N + col] = f2b(acc[mt][nt][j]);
      }
    }
  }
}

// ------- fused split-K(3) reduce + bias + residual + LayerNorm, bf16 partials -------
// 192 active lanes; u16x4/f32x4-vectorized.
// RES_BF16: residual read as bf16 (within-layer x residual; regenerated through LN each
//           layer so its rounding enters the persistent stream only once per layer).
// OUT_F32:  also store fp32 (needed only for the persistent h stream / LN2 output).
template <bool RES_BF16, bool OUT_F32>
__global__ __launch_bounds__(256)
void ln_red_h(const u16* __restrict__ P0, const u16* __restrict__ P1,
              const u16* __restrict__ P2,
              const float* __restrict__ bias, const void* __restrict__ res,
              const float* __restrict__ g, const float* __restrict__ bv,
              float* __restrict__ o32, u16* __restrict__ obf) {
  const int row = blockIdx.x;
  const size_t b4 = (size_t)row * 192;   // 4-wide index of row start
  const int tid = threadIdx.x;
  f32x4 vv = {0.f, 0.f, 0.f, 0.f};
  float ls = 0.f, lq = 0.f;
  if (tid < 192) {
    u16x4 a = ((const u16x4*)P0)[b4 + tid];
    u16x4 b = ((const u16x4*)P1)[b4 + tid];
    u16x4 p = ((const u16x4*)P2)[b4 + tid];
    f32x4 c;
    if constexpr (RES_BF16) {
      u16x4 cr = ((const u16x4*)res)[b4 + tid];
#pragma unroll
      for (int k = 0; k < 4; ++k) c[k] = b2f(cr[k]);
    } else {
      c = ((const f32x4*)res)[b4 + tid];
    }
    f32x4 d = ((const f32x4*)bias)[tid];
#pragma unroll
    for (int k = 0; k < 4; ++k)
      vv[k] = b2f(a[k]) + b2f(b[k]) + b2f(p[k]) + c[k] + d[k];
    ls = vv[0] + vv[1] + vv[2] + vv[3];
    lq = vv[0]*vv[0] + vv[1]*vv[1] + vv[2]*vv[2] + vv[3]*vv[3];
  }
  float s = wred_sum(ls);
  float s2 = wred_sum(lq);
  __shared__ float rs[4], rq[4];
  const int wv = tid >> 6, lane = tid & 63;
  if (lane == 0) { rs[wv] = s; rq[wv] = s2; }
  __syncthreads();
  float S1 = rs[0] + rs[1] + rs[2] + rs[3];
  float S2 = rq[0] + rq[1] + rq[2] + rq[3];
  float mean = S1 * (1.0f / 768.0f);
  float var = S2 * (1.0f / 768.0f) - mean * mean;
  float inv = rsqrtf(var + 1e-5f);
  if (tid < 192) {
    f32x4 gg = ((const f32x4*)g)[tid];
    f32x4 bb = ((const f32x4*)bv)[tid];
    f32x4 y;
    u16x4 ob;
#pragma unroll
    for (int k = 0; k < 4; ++k) {
      y[k] = (vv[k] - mean) * inv * gg[k] + bb[k];
      ob[k] = f2b(y[k]);
    }
    if constexpr (OUT_F32) ((f32x4*)o32)[b4 + tid] = y;
    ((u16x4*)obf)[b4 + tid] = ob;
  }
}

// ------- per-layer weight prep: fp32 [K,N] -> bf16 [N,K] for all 6 matrices -------
__global__ void prep_layer(const float* __restrict__ Wq, const float* __restrict__ Wk,
                           const float* __restrict__ Wv, const float* __restrict__ Wo,
                           const float* __restrict__ W1, const float* __restrict__ W2,
                           u16* __restrict__ qkvT, u16* __restrict__ woT,
                           u16* __restrict__ w1T, u16* __restrict__ w2T) {
  __shared__ float tbuf[32][33];
  const int t = blockIdx.x;
  const float* src; u16* dst; int K, N, nt, kt;
  if (t < 2304) {
    int seg = t / 576, r = t % 576;
    nt = r % 24; kt = r / 24; K = 768; N = 768;
    if (seg == 0)      { src = Wq; dst = qkvT; }
    else if (seg == 1) { src = Wk; dst = qkvT + (size_t)768 * 768; }
    else if (seg == 2) { src = Wv; dst = qkvT + (size_t)2 * 768 * 768; }
    else               { src = Wo; dst = woT; }
  } else if (t < 4608) {
    int r = t - 2304; nt = r % 96; kt = r / 96;
    K = 768; N = 3072; src = W1; dst = w1T;
  } else {
    int r = t - 4608; nt = r % 24; kt = r / 24;
    K = 3072; N = 768; src = W2; dst = w2T;
  }
  const int n0 = nt * 32, k0 = kt * 32;
  const int tx = threadIdx.x, ty = threadIdx.y;  // (32,8)
#pragma unroll
  for (int i = 0; i < 4; ++i)
    tbuf[ty + i * 8][tx] = src[(size_t)(k0 + ty + i * 8) * N + n0 + tx];
  __syncthreads();
#pragma unroll
  for (int i = 0; i < 4; ++i)
    dst[(size_t)(n0 + ty + i * 8) * K + k0 + tx] = f2b(tbuf[tx][ty + i * 8]);
}

__global__ void convert_bf(const float* __restrict__ s, u16* __restrict__ d, size_t n) {
  size_t i = (size_t)blockIdx.x * 256 + threadIdx.x;
  if (i < n) d[i] = f2b(s[i]);
}

// ---- head_W transpose: fp32 [768,1000] -> fp32 [1000,768] ----
__global__ void transpose_head(const float* __restrict__ src, float* __restrict__ dst) {
  __shared__ float tbuf[32][33];
  const int n0 = blockIdx.x * 32, k0 = blockIdx.y * 32;
  const int tx = threadIdx.x, ty = threadIdx.y;  // (32,8)
#pragma unroll
  for (int i = 0; i < 4; ++i) {
    int k = k0 + ty + i * 8, n = n0 + tx;
    if (n < 1000) tbuf[ty + i * 8][tx] = src[(size_t)k * 1000 + n];
  }
  __syncthreads();
#pragma unroll
  for (int i = 0; i < 4; ++i) {
    int n = n0 + ty + i * 8, k = k0 + tx;
    if (n < 1000) dst[(size_t)n * 768 + k] = tbuf[tx][ty + i * 8];
  }
}

// ---------------- patch im2col: A[b*196+p][c*256+ph*16+pw] ----------------
__global__ void im2col(const float* __restrict__ x, u16* __restrict__ A) {
  size_t idx = (size_t)blockIdx.x * 256 + threadIdx.x;
  if (idx >= (size_t)6272 * 768) return;
  int k = (int)(idx % 768); size_t row = idx / 768;
  int b = (int)(row / 196), p = (int)(row % 196);
  int py = p / 14, px = p % 14;
  int c = k >> 8, rem = k & 255, ph = rem >> 4, pw = rem & 15;
  float v = x[(((size_t)b * 3 + c) * 224 + (py * 16 + ph)) * 224 + (px * 16 + pw)];
  A[idx] = f2b(v);
}

// ---------------- h0 = concat(cls, patches) + pos ----------------
__global__ void assemble_h0(const float* __restrict__ pout, const float* __restrict__ cls,
                            const float* __restrict__ pos, float* __restrict__ h32,
                            u16* __restrict__ hbf) {
  const int row = blockIdx.x;           // 0..6303
  const int b = row / NTOK, n = row % NTOK;
  for (int c = threadIdx.x; c < EMB; c += 256) {
    float v;
    if (n == 0) v = cls[c] + pos[c];
    else v = pout[((size_t)b * 196 + (n - 1)) * EMB + c] + pos[(size_t)n * EMB + c];
    h32[(size_t)row * EMB + c] = v;
    hbf[(size_t)row * EMB + c] = f2b(v);
  }
}

// ------- vT[bh][d][n] = v[b][n][h][d] via LDS tile transpose (both sides coalesced) -------
// grid (14, 384): blockIdx.x = dt*7 + nt  (dt 0..1 selects 32-d half, nt 0..6 selects 32-n tile)
__global__ void build_vT2(const u16* __restrict__ qkv, u16* __restrict__ vT) {
  __shared__ u16 tbuf[32][34];
  const int t = blockIdx.x;
  const int dt = t / 7, nt = t % 7;
  const int bh = blockIdx.y;
  const int b = bh / NHEAD, h = bh % NHEAD;
  const int tx = threadIdx.x, ty = threadIdx.y;  // (32,8)
  const u16* vbase = qkv + (size_t)b * NTOK * 2304 + 1536 + h * HDIM + dt * 32;
#pragma unroll
  for (int i = 0; i < 4; ++i) {
    int nrow = ty + i * 8;                // 0..31 (nn-local)
    int nn = nt * 32 + nrow;
    u16 v = 0;
    if (nn < NTOK) v = vbase[(size_t)nn * 2304 + tx];   // tx = d-local: coalesced (2B stride)
    tbuf[nrow][tx] = v;
  }
  __syncthreads();
  u16* obase = vT + ((size_t)bh * HDIM + dt * 32) * NPAD + nt * 32;
#pragma unroll
  for (int i = 0; i < 4; ++i) {
    int drow = ty + i * 8;                // 0..31 (d-local)
    obase[(size_t)drow * NPAD + tx] = tbuf[tx][drow];   // tx = nn-local: coalesced
  }
}

// ---------------- fused scores + softmax for a 32-q-row slab of one (b,h) ----------------
__global__ __launch_bounds__(256)
void attn_sm(const u16* __restrict__ qkv, u16* __restrict__ P) {
  __shared__ __align__(16) char kf[13 * 2 * 1024];  // 26KB, K fragments
  __shared__ __align__(16) char qf[2 * 2 * 1024];   // 4KB,  Q fragments
  __shared__ float S[32][NPAD + 4];                 // 28.5KB (bank-conflict pad)
  const int bh = blockIdx.y;
  const int b = bh / NHEAD, h = bh % NHEAD;
  const int qb = blockIdx.x;  // 0..6
  const int tid = threadIdx.x, lane = tid & 63, wid = tid >> 6;
  const int r15 = lane & 15, khi = lane >> 4;

  const u16* qbase = qkv + (size_t)b * NTOK * 2304 + h * HDIM;
  const u16* kbase = qbase + 768;

  for (int i = wid; i < 26; i += 4) {           // stage K: 13 subtiles x 2 kslices
    int sub = i >> 1, ks = i & 1;
    int row = sub * 16 + r15; if (row > 196) row = 196;
    gload16(kbase + (size_t)row * 2304 + ks * 32 + khi * 8, &kf[(size_t)i * 1024]);
  }
  {                                             // stage Q: 2 subtiles x 2 kslices
    int i = wid;  // 0..3
    int sub = i >> 1, ks = i & 1;
    int row = qb * 32 + sub * 16 + r15; if (row > 196) row = 196;
    gload16(qbase + (size_t)row * 2304 + ks * 32 + khi * 8, &qf[(size_t)i * 1024]);
  }
  __syncthreads();

  const float scale = 0.03608439182435161f;  // 1/sqrt(768)
  for (int t = wid; t < 26; t += 4) {
    int qi = t / 13, ki = t % 13;
    f32x4 acc = {};
    bf16x8_t aq0 = *(const bf16x8_t*)&qf[(qi * 2 + 0) * 1024 + lane * 16];
    bf16x8_t aq1 = *(const bf16x8_t*)&qf[(qi * 2 + 1) * 1024 + lane * 16];
    bf16x8_t bk0 = *(const bf16x8_t*)&kf[(ki * 2 + 0) * 1024 + lane * 16];
    bf16x8_t bk1 = *(const bf16x8_t*)&kf[(ki * 2 + 1) * 1024 + lane * 16];
    acc = __builtin_amdgcn_mfma_f32_16x16x32_bf16(aq0, bk0, acc, 0, 0, 0);
    acc = __builtin_amdgcn_mfma_f32_16x16x32_bf16(aq1, bk1, acc, 0, 0, 0);
#pragma unroll
    for (int j = 0; j < 4; ++j) S[qi * 16 + khi * 4 + j][ki * 16 + r15] = acc[j] * scale;
  }
  __syncthreads();

  for (int i = 0; i < 8; ++i) {
    const int r = wid * 8 + i;
    const int q = qb * 32 + r;
    if (q > 196) continue;
    float vals[4]; float m = -1e30f;
#pragma unroll
    for (int c = 0; c < 4; ++c) {
      int col = lane + c * 64;
      float v = (col < NTOK) ? S[r][col] : -1e30f;
      vals[c] = v; m = fmaxf(m, v);
    }
#pragma unroll
    for (int o = 32; o > 0; o >>= 1) m = fmaxf(m, __shfl_xor(m, o));
    float s = 0.f;
#pragma unroll
    for (int c = 0; c < 4; ++c) { float e = __expf(vals[c] - m); vals[c] = e; s += e; }
    s = wred_sum(s);
    float inv = 1.f / s;
    u16* prow = P + ((size_t)bh * NTOK + q) * NPAD;
#pragma unroll
    for (int c = 0; c < 4; ++c) {
      int col = lane + c * 64;
      if (col < NPAD) prow[col] = f2b(vals[c] * inv);
    }
  }
}

// ------- PV half-split: grid (2, 384); z selects P subtiles 0..6 / 7..12 -------
__global__ __launch_bounds__(256)
void attn_pv_half(const u16* __restrict__ P, const u16* __restrict__ vT,
                  u16* __restrict__ out) {
  __shared__ __align__(16) char lds[2][11 * 1024];  // P subtiles 0..6, V subtiles 7..10
  const int z = blockIdx.x;          // 0: q-subtiles 0..6, 1: 7..12
  const int bh = blockIdx.y;
  const int b = bh / NHEAD, h = bh % NHEAD;
  const int qoff = z ? 7 : 0;
  const int NQ = z ? 6 : 7;
  const int tid = threadIdx.x, lane = tid & 63, wid = tid >> 6;
  const int r15 = lane & 15, khi = lane >> 4;
  const u16* Pb = P + (size_t)bh * NTOK * NPAD;
  const u16* Vb = vT + (size_t)bh * HDIM * NPAD;

  f32x4 acc[2][4] = {};
  auto stage = [&](int buf, int kt) {
    for (int i = wid; i < 11; i += 4) {
      const u16* g;
      if (i < 7) { int sub = qoff + i; if (sub > 12) sub = 12;   // z=1,i=6: dup, never stored
                   int row = sub * 16 + r15; if (row > 196) row = 196;
                   g = Pb + (size_t)row * NPAD + kt * 32 + khi * 8; }
      else       { int row = (i - 7) * 16 + r15;
                   g = Vb + (size_t)row * NPAD + kt * 32 + khi * 8; }
      gload16(g, &lds[buf][i * 1024]);
    }
  };
  stage(0, 0);
  __syncthreads();
  for (int kt = 0; kt < 7; ++kt) {
    const int cur = kt & 1;
    if (kt + 1 < 7) stage(cur ^ 1, kt + 1);
    bf16x8_t bb[4];
#pragma unroll
    for (int di = 0; di < 4; ++di)
      bb[di] = *(const bf16x8_t*)&lds[cur][(7 + di) * 1024 + lane * 16];
#pragma unroll
    for (int s = 0; s < 2; ++s) {
      int ql = wid + s * 4;
      if (ql < NQ) {
        bf16x8_t a = *(const bf16x8_t*)&lds[cur][ql * 1024 + lane * 16];
#pragma unroll
        for (int di = 0; di < 4; ++di)
          acc[s][di] = __builtin_amdgcn_mfma_f32_16x16x32_bf16(a, bb[di], acc[s][di], 0, 0, 0);
      }
    }
    __syncthreads();
  }
#pragma unroll
  for (int s = 0; s < 2; ++s) {
    int ql = wid + s * 4;
    if (ql >= NQ) continue;
    const int qi = qoff + ql;
#pragma unroll
    for (int di = 0; di < 4; ++di) {
      int col = h * HDIM + di * 16 + r15;
#pragma unroll
      for (int j = 0; j < 4; ++j) {
        int q = qi * 16 + khi * 4 + j;
        if (q < NTOK) out[((size_t)b * NTOK + q) * EMB + col] = f2b(acc[s][di][j]);
      }
    }
  }
}

// ---------------- LN of the 32 cls rows -> cls_ln[32][768] fp32 ----------------
__global__ __launch_bounds__(256)
void ln_cls(const float* __restrict__ h32, const float* __restrict__ hg,
            const float* __restrict__ hb, float* __restrict__ cls_ln) {
  const int b = blockIdx.x;
  const float* xr = h32 + (size_t)b * NTOK * EMB;  // row n=0
  const int tid = threadIdx.x;
  float v0 = xr[tid], v1 = xr[tid + 256], v2 = xr[tid + 512];
  float s = wred_sum(v0 + v1 + v2);
  float s2 = wred_sum(v0 * v0 + v1 * v1 + v2 * v2);
  __shared__ float rs[4], rq[4];
  const int wid = tid >> 6, lane = tid & 63;
  if (lane == 0) { rs[wid] = s; rq[wid] = s2; }
  __syncthreads();
  float S1 = rs[0] + rs[1] + rs[2] + rs[3];
  float S2 = rq[0] + rq[1] + rq[2] + rq[3];
  float mean = S1 * (1.0f / 768.0f);
  float var = S2 * (1.0f / 768.0f) - mean * mean;
  float inv = rsqrtf(var + 1e-5f);
  cls_ln[(size_t)b * EMB + tid]       = (v0 - mean) * inv * hg[tid]       + hb[tid];
  cls_ln[(size_t)b * EMB + tid + 256] = (v1 - mean) * inv * hg[tid + 256] + hb[tid + 256];
  cls_ln[(size_t)b * EMB + tid + 512] = (v2 - mean) * inv * hg[tid + 512] + hb[tid + 512];
}

// -------- head2: out[b][j] = dot(cls_ln[b], hWT[j]) + bias[j]; one wave per output --------
__global__ __launch_bounds__(256)
void head2(const float* __restrict__ cls_ln, const float* __restrict__ hWT,
           const float* __restrict__ bias, float* __restrict__ out) {
  __shared__ float t[EMB];
  const int b = blockIdx.y;
  const int tid = threadIdx.x, lane = tid & 63, wid = tid >> 6;
  t[tid] = cls_ln[(size_t)b * EMB + tid];
  t[tid + 256] = cls_ln[(size_t)b * EMB + tid + 256];
  t[tid + 512] = cls_ln[(size_t)b * EMB + tid + 512];
  __syncthreads();
  const int j = blockIdx.x * 4 + wid;   // 250*4 = 1000 exactly
  const float* wr = hWT + (size_t)j * EMB;
  float a = 0.f;
#pragma unroll
  for (int i = 0; i < 12; ++i) {
    int e = lane + i * 64;
    a += t[e] * wr[e];
  }
  a = wred_sum(a);
  if (lane == 0) out[(size_t)b * 1000 + j] = a + bias[j];
}

extern "C" void kernel_launch(void* const* d_in, const int* in_sizes, int n_in,
                              void* d_out, int out_size, void* d_ws, size_t ws_size,
                              hipStream_t stream) {
  const float* x      = (const float*)d_in[0];
  const float* conv_w = (const float*)d_in[1];
  const float* conv_b = (const float*)d_in[2];
  const float* cls    = (const float*)d_in[3];
  const float* pos    = (const float*)d_in[4];
  const float* Wq     = (const float*)d_in[5];
  const float* Wk     = (const float*)d_in[6];
  const float* Wv     = (const float*)d_in[7];
  const float* Wo     = (const float*)d_in[8];
  const float* bo     = (const float*)d_in[9];
  const float* ln1g   = (const float*)d_in[10];
  const float* ln1b   = (const float*)d_in[11];
  const float* W1     = (const float*)d_in[12];
  const float* b1     = (const float*)d_in[13];
  const float* W2     = (const float*)d_in[14];
  const float* b2     = (const float*)d_in[15];
  const float* ln2g   = (const float*)d_in[16];
  const float* ln2b   = (const float*)d_in[17];
  const float* hg     = (const float*)d_in[18];
  const float* hb     = (const float*)d_in[19];
  const float* hW     = (const float*)d_in[20];
  const float* hbias  = (const float*)d_in[21];

  char* ws = (char*)d_ws;
  size_t off = 0;
  auto alloc = [&](size_t bytes) { void* p = ws + off; off += (bytes + 255) & ~(size_t)255; return p; };

  // per-layer transposed weights (reused every layer)
  u16*   qkvT = (u16*)alloc((size_t)2304 * 768 * 2);            // 3.54 MB
  u16*   woTl = (u16*)alloc((size_t)768 * 768 * 2);             // 1.18 MB
  u16*   w1Tl = (u16*)alloc((size_t)3072 * 768 * 2);            // 4.72 MB
  u16*   w2Tl = (u16*)alloc((size_t)768 * 3072 * 2);            // 4.72 MB
  u16*   cw   = (u16*)alloc((size_t)768 * 768 * 2);             // 1.18 MB
  float* h32  = (float*)alloc((size_t)ROWS * EMB * 4);          // 19.4 MB (persistent fp32 stream)
  u16*   hbf  = (u16*)alloc((size_t)ROWS * EMB * 2);            // 9.7 MB
  u16*   qkv  = (u16*)alloc((size_t)ROWS * 2304 * 2);           // 29.0 MB (also FFN2 bf16 partials)
  u16*   vT   = (u16*)alloc((size_t)384 * HDIM * NPAD * 2);     // 11.0 MB
  // union region (38.8MB): {Pbuf 33.9} OR {Wo bf16 partials 3x9.7} OR {mid 38.7} OR {pout 19.3}
  char*  big  = (char*)alloc(2 * (size_t)ROWS * EMB * 4);       // 38.8 MB
  u16*   Pbuf = (u16*)big;
  u16*   mid  = (u16*)big;                   // FFN hidden, alive only after attn done
  float* pout = (float*)big;                 // setup-phase patch GEMM output
  u16*   woPh0 = (u16*)big;                              // Wo bf16 partial 0 (Pbuf dead)
  u16*   woPh1 = (u16*)(big + (size_t)ROWS * EMB * 2);   // partial 1
  u16*   woPh2 = (u16*)(big + (size_t)2 * ROWS * EMB * 2); // partial 2 (29.1MB total < 38.8)
  u16*   att  = (u16*)alloc((size_t)ROWS * EMB * 2);            // 9.7 MB  (aliased w/ xbf)
  u16*   xbf  = att;                         // bf16 x: FFN1 input AND LN2 residual
  float* hWT  = (float*)alloc((size_t)1000 * EMB * 4);          // 3.07 MB
  float* clsl = (float*)alloc((size_t)32 * EMB * 4);            // 98 KB
  u16*   Apatch = qkv;                       // setup-phase im2col output (9.6MB < 29MB)
  // FFN2 bf16 partials live in qkv (dead after attention; 3 x 9.68MB = 29.04MB = qkv size)
  u16*   f2Ph0 = qkv;
  u16*   f2Ph1 = qkv + (size_t)ROWS * EMB;
  u16*   f2Ph2 = qkv + (size_t)2 * ROWS * EMB;

  if (off > ws_size) return;  // workspace too small: fail validation cleanly, never write OOB

  // ---- conv weight + head weight + patch embed (256x128 pipelined GEMM) ----
  convert_bf<<<2304, 256, 0, stream>>>(conv_w, cw, (size_t)768 * 768);
  transpose_head<<<dim3(32, 24), dim3(32, 8), 0, stream>>>(hW, hWT);
  im2col<<<18816, 256, 0, stream>>>(x, Apatch);
  gemm_bt2<true, false, false><<<dim3(6, 25), 512, 0, stream>>>(
      Apatch, cw, pout, conv_b, 6272, 768, 768);
  assemble_h0<<<ROWS, 256, 0, stream>>>(pout, cls, pos, h32, hbf);

  // ---- transformer layers ----
  for (int l = 0; l < 12; ++l) {
    const size_t wo = (size_t)l * 768 * 768;
    prep_layer<<<6912, dim3(32, 8), 0, stream>>>(
        Wq + wo, Wk + wo, Wv + wo, Wo + wo,
        W1 + (size_t)l * 768 * 3072, W2 + (size_t)l * 3072 * 768,
        qkvT, woTl, w1Tl, w2Tl);
    // QKV: 256x128 8-wave tile, 2-deep counted-vmcnt pipeline, issue-early staging
    gemm_bt2<false, false, true><<<dim3(18, 25), 512, 0, stream>>>(
        hbf, qkvT, qkv, nullptr, ROWS, 2304, 768);
    build_vT2<<<dim3(14, 384), dim3(32, 8), 0, stream>>>(qkv, vT);
    attn_sm<<<dim3(7, 384), 256, 0, stream>>>(qkv, Pbuf);
    attn_pv_half<<<dim3(2, 384), 256, 0, stream>>>(Pbuf, vT, att);
    // Wo projection, split-K=3 (Kh=256), bf16 partials; LN1: fp32 res (h32), bf16-only out
    gemm_bt_sk_h<<<dim3(6, 50, 3), 256, 0, stream>>>(att, woTl, woPh0, woPh1, woPh2, ROWS, 768, 768);
    ln_red_h<false, false><<<ROWS, 256, 0, stream>>>(
        woPh0, woPh1, woPh2, bo + (size_t)l * 768, h32,
        ln1g + (size_t)l * 768, ln1b + (size_t)l * 768, nullptr, xbf);
    // FFN1: 256x128 8-wave tile, fused bias+relu+bf16
    gemm_bt2<true, true, true><<<dim3(24, 25), 512, 0, stream>>>(
        xbf, w1Tl, mid, b1 + (size_t)l * 3072, ROWS, FFDIM, 768);
    // FFN2, split-K=3 (Kh=1024), bf16 partials (in dead qkv); LN2: bf16 res (xbf),
    // fp32+bf16 out (persistent h stream stays fp32)
    gemm_bt_sk_h<<<dim3(6, 50, 3), 256, 0, stream>>>(mid, w2Tl, f2Ph0, f2Ph1, f2Ph2, ROWS, 768, FFDIM);
    ln_red_h<true, true><<<ROWS, 256, 0, stream>>>(
        f2Ph0, f2Ph1, f2Ph2, b2 + (size_t)l * 768, xbf,
        ln2g + (size_t)l * 768, ln2b + (size_t)l * 768, h32, hbf);
  }

  // ---- classifier head ----
  ln_cls<<<32, 256, 0, stream>>>(h32, hg, hb, clsl);
  head2<<<dim3(250, 32), 256, 0, stream>>>(clsl, hWT, hbias, (float*)d_out);
}